// Round 15
// baseline (869.731 us; speedup 1.0000x reference)
//
#include <hip/hip_runtime.h>
#include <math.h>

// PatchTST-style fused forward, f32 in/out, bf16 MFMA compute.
// Round-21: RESUBMIT of round-20 (container failed twice = infra flake;
// kernel has no new legality risk vs r19: LDS unchanged at 74,240B which
// launched fine in r17/r19; only deltas are a register-level prefetch and
// exp2f). r19 base = 852us, 2 blk/CU, VGPR 112, no spill.
//  1. Depth-1 V prefetch: load vv[si+1] before consuming vv[si] (+8 regs,
//     r18 showed +16 spills; +8 fits the ~12-reg headroom). 30 exposed
//     ~120cy LDS latencies become ~96cy overlapped.
//  2. exp->exp2 fold (free): q pre-scaled by ATTN_SCALE*log2e; softmax via
//     exp2f(sc-mx) is identical math (uniform logit scale cancels in the
//     ratio; consistent across accumulated layers).
// Tripwire: WRITE_SIZE must stay 14,445 KB.
// Ledger: 2 blk/CU frontier (HW {128,256} reg quantization, m69); arch cap
// 128 @ wpe(2); setprio -2% (r15); intra-phase shave neutral (r16); K/V
// hoist +7us (r17); V-fusion spills (r14/r18); QK fusion+barrier cut -5us (r19).

typedef unsigned short u16;
typedef __attribute__((ext_vector_type(8))) short short8;
typedef __attribute__((ext_vector_type(4))) float floatx4;

// ATTN_SCALE * log2(e) = (8^-0.5) * 1.4426950408889634
#define QSCALE 0.5101087004564975f
#define SB 136        // bf16 LDS row stride: 272B = 68 dwords, 68%32=4 -> bank rotation
#define BUFSZ (30*SB) // one 30-row bf16 buffer, in u16 units

#define MFMA_BF16 __builtin_amdgcn_mfma_f32_16x16x32_bf16

__device__ __forceinline__ u16 f2bf(float f){
  union{ __bf16 b; u16 u; } v; v.b = (__bf16)f;   // RNE, hw cvt
  return v.u;
}
__device__ __forceinline__ float bf2f(u16 h){
  union{unsigned u; float f;} v; v.u = ((unsigned)h)<<16;
  return v.f;
}
// packed pair f32,f32 -> bf16x2 in one u32 (v_cvt_pk_bf16_f32)
__device__ __forceinline__ unsigned pk2bf(float lo, float hi){
  union{ __bf16 b[2]; unsigned u; } v;
  v.b[0] = (__bf16)lo; v.b[1] = (__bf16)hi;
  return v.u;
}
// d = a.bf16[0]*b.bf16[0] + a.bf16[1]*b.bf16[1] + c
__device__ __forceinline__ float dot2bf(unsigned a, unsigned b, float c){
  float d;
  asm("v_dot2_f32_bf16 %0, %1, %2, %3" : "=v"(d) : "v"(a), "v"(b), "v"(c));
  return d;
}
__device__ __forceinline__ float gelu_f(float x){   // tanh-form gelu (sigmoid identity)
  float u = x*(1.f + 0.044715f*x*x);
  float e = __expf(-1.5957691216057308f*u);
  return x/(1.f+e);
}

// 8 f32 -> bf16 fragment (16B-aligned source)
__device__ __forceinline__ short8 cvt8(const float* ap){
  floatx4 f0 = *(const floatx4*)ap;
  floatx4 f1 = *(const floatx4*)(ap+4);
  short8 a;
  a[0]=(short)f2bf(f0[0]); a[1]=(short)f2bf(f0[1]);
  a[2]=(short)f2bf(f0[2]); a[3]=(short)f2bf(f0[3]);
  a[4]=(short)f2bf(f1[0]); a[5]=(short)f2bf(f1[1]);
  a[6]=(short)f2bf(f1[2]); a[7]=(short)f2bf(f1[3]);
  return a;
}
__device__ __forceinline__ short8 loadB(const u16* p){ return *(const short8*)p; }
__device__ __forceinline__ short8 loadB(const float* p){ return cvt8(p); }

// store 4 acc rows ((acc+bias)*oscale) as bf16; rows >=30 skipped
__device__ __forceinline__ void epi(u16* out, floatx4 acc, float bv, float oscale,
                                    int rt, int qd, int col){
  #pragma unroll
  for (int r=0;r<4;++r){
    const int row = rt*16+qd*4+r;
    if (row<30) out[row*SB+col] = f2bf((acc[r]+bv)*oscale);
  }
}

// out(30x128) = A(30x128 LDS bf16, rows 30/31 read-over) @ W^T + bias, *oscale.
// 4 waves: wave covers cols {wave*16+m, 64+wave*16+m}; kt-outer, ct-batched.
template<typename WT>
__device__ __forceinline__ void gemm2(const u16* A, const WT* __restrict__ W,
                                      const float* __restrict__ bias, u16* out,
                                      int wave, int lane, float oscale){
  const int m=lane&15, qd=lane>>4, c0=wave*16+m;
  floatx4 acc[2][2] = {{{0.f,0.f,0.f,0.f},{0.f,0.f,0.f,0.f}},
                       {{0.f,0.f,0.f,0.f},{0.f,0.f,0.f,0.f}}};
  #pragma unroll
  for (int kt=0;kt<4;++kt){
    short8 b0 = loadB(W + c0*128       + kt*32 + qd*8);
    short8 b1 = loadB(W + (c0+64)*128  + kt*32 + qd*8);
    #pragma unroll
    for (int rt=0;rt<2;++rt){
      short8 a = *(const short8*)(A + (rt*16+m)*SB + kt*32 + qd*8);
      acc[0][rt] = MFMA_BF16(a, b0, acc[0][rt], 0,0,0);
      acc[1][rt] = MFMA_BF16(a, b1, acc[1][rt], 0,0,0);
    }
  }
  #pragma unroll
  for (int ct=0;ct<2;++ct){
    const int col = c0 + ct*64;
    const float bv = bias[col];
    #pragma unroll
    for (int rt=0;rt<2;++rt) epi(out, acc[ct][rt], bv, oscale, rt, qd, col);
  }
}

// k and v gemms from shared A = x_s
template<typename WT>
__device__ __forceinline__ void gemm_kv(const u16* A,
                                        const WT* __restrict__ Wk, const float* __restrict__ bk,
                                        const WT* __restrict__ Wv, const float* __restrict__ bv_,
                                        u16* outk, u16* outv, int wave, int lane){
  const int m=lane&15, qd=lane>>4, c0=wave*16+m;
  floatx4 acck[2][2] = {{{0.f,0.f,0.f,0.f},{0.f,0.f,0.f,0.f}},
                        {{0.f,0.f,0.f,0.f},{0.f,0.f,0.f,0.f}}};
  floatx4 accv[2][2] = {{{0.f,0.f,0.f,0.f},{0.f,0.f,0.f,0.f}},
                        {{0.f,0.f,0.f,0.f},{0.f,0.f,0.f,0.f}}};
  #pragma unroll
  for (int kt=0;kt<4;++kt){
    short8 bk0 = loadB(Wk + c0*128      + kt*32 + qd*8);
    short8 bk1 = loadB(Wk + (c0+64)*128 + kt*32 + qd*8);
    short8 bv0 = loadB(Wv + c0*128      + kt*32 + qd*8);
    short8 bv1 = loadB(Wv + (c0+64)*128 + kt*32 + qd*8);
    #pragma unroll
    for (int rt=0;rt<2;++rt){
      short8 a = *(const short8*)(A + (rt*16+m)*SB + kt*32 + qd*8);
      acck[0][rt] = MFMA_BF16(a, bk0, acck[0][rt], 0,0,0);
      acck[1][rt] = MFMA_BF16(a, bk1, acck[1][rt], 0,0,0);
      accv[0][rt] = MFMA_BF16(a, bv0, accv[0][rt], 0,0,0);
      accv[1][rt] = MFMA_BF16(a, bv1, accv[1][rt], 0,0,0);
    }
  }
  #pragma unroll
  for (int ct=0;ct<2;++ct){
    const int col = c0 + ct*64;
    const float bkb = bk[col], bvb = bv_[col];
    #pragma unroll
    for (int rt=0;rt<2;++rt){
      epi(outk, acck[ct][rt], bkb, 1.f, rt, qd, col);
      epi(outv, accv[ct][rt], bvb, 1.f, rt, qd, col);
    }
  }
}

// FF up: h = pred@W1^T (256 cols); writes ag = a * gelu(gate) directly.
template<typename WT>
__device__ __forceinline__ void gemm_h(const u16* A, const WT* __restrict__ W1,
                                       const float* __restrict__ b1, u16* out,
                                       int wave, int lane){
  const int m=lane&15, qd=lane>>4, c0=wave*16+m;
  floatx4 acca[2][2] = {{{0.f,0.f,0.f,0.f},{0.f,0.f,0.f,0.f}},
                        {{0.f,0.f,0.f,0.f},{0.f,0.f,0.f,0.f}}};
  floatx4 accg[2][2] = {{{0.f,0.f,0.f,0.f},{0.f,0.f,0.f,0.f}},
                        {{0.f,0.f,0.f,0.f},{0.f,0.f,0.f,0.f}}};
  #pragma unroll
  for (int kt=0;kt<4;++kt){
    short8 ba0 = loadB(W1 + c0*128        + kt*32 + qd*8);
    short8 ba1 = loadB(W1 + (c0+64)*128   + kt*32 + qd*8);
    short8 bg0 = loadB(W1 + (c0+128)*128  + kt*32 + qd*8);
    short8 bg1 = loadB(W1 + (c0+192)*128  + kt*32 + qd*8);
    #pragma unroll
    for (int rt=0;rt<2;++rt){
      short8 a = *(const short8*)(A + (rt*16+m)*SB + kt*32 + qd*8);
      acca[0][rt] = MFMA_BF16(a, ba0, acca[0][rt], 0,0,0);
      acca[1][rt] = MFMA_BF16(a, ba1, acca[1][rt], 0,0,0);
      accg[0][rt] = MFMA_BF16(a, bg0, accg[0][rt], 0,0,0);
      accg[1][rt] = MFMA_BF16(a, bg1, accg[1][rt], 0,0,0);
    }
  }
  #pragma unroll
  for (int ct=0;ct<2;++ct){
    const int ca = c0 + ct*64;
    const float bab = b1[ca], bgb = b1[128+ca];
    #pragma unroll
    for (int rt=0;rt<2;++rt){
      #pragma unroll
      for (int r=0;r<4;++r){
        const int row = rt*16+qd*4+r;
        if (row<30){
          float a = acca[ct][rt][r]+bab;
          float g = accg[ct][rt][r]+bgb;
          out[row*SB+ca] = f2bf(a * gelu_f(g));
        }
      }
    }
  }
}

// pred = LN(pred + bf16(add)) * g + be; pred lives in registers p0/p1
// (thread owns rows {wave+4k}, cols {lane, lane+64}); maintains predb mirror.
__device__ __forceinline__ void ln_res_reg(float (&p0)[8], float (&p1)[8],
                                           const u16* add, u16* predb,
                                           const float* __restrict__ g, const float* __restrict__ be,
                                           int wave, int lane){
  #pragma unroll
  for (int idx=0; idx<8; ++idx){
    const int row = wave + idx*4;
    if (row < 30){
      float v0 = p0[idx] + bf2f(add[row*SB+lane]);
      float v1 = p1[idx] + bf2f(add[row*SB+lane+64]);
      float s = v0+v1, s2 = v0*v0+v1*v1;
      #pragma unroll
      for (int off=32; off>0; off>>=1){ s += __shfl_xor(s,off,64); s2 += __shfl_xor(s2,off,64); }
      float m = s*(1.f/128.f);
      float var = s2*(1.f/128.f) - m*m;
      float rstd = rsqrtf(var + 1e-5f);
      float o0 = (v0-m)*rstd*g[lane]    + be[lane];
      float o1 = (v1-m)*rstd*g[lane+64] + be[lane+64];
      p0[idx] = o0; p1[idx] = o1;
      predb[row*SB+lane]    = f2bf(o0);
      predb[row*SB+lane+64] = f2bf(o1);
    }
  }
}

// f32 -> bf16 weight staging
__global__ void cvtw(const float* __restrict__ Wq, const float* __restrict__ Wk,
                     const float* __restrict__ Wv, const float* __restrict__ Wo,
                     const float* __restrict__ W1, const float* __restrict__ W2,
                     u16* __restrict__ ws){
  const int i = blockIdx.x*256 + threadIdx.x;   // grid covers exactly 344064
  float v;
  if      (i < 49152)  v = Wq[i];
  else if (i < 98304)  v = Wk[i-49152];
  else if (i < 147456) v = Wv[i-98304];
  else if (i < 196608) v = Wo[i-147456];
  else if (i < 294912) v = W1[i-196608];
  else                 v = W2[i-294912];
  ws[i] = f2bf(v);
}

template<typename WT>
__global__ void
__attribute__((amdgpu_flat_work_group_size(256,256), amdgpu_waves_per_eu(2)))
ts_fused(
  const float* __restrict__ z,    const float* __restrict__ WPw, const float* __restrict__ WPb,
  const float* __restrict__ PE,   const float* __restrict__ dums,
  const WT*    __restrict__ Wq_a, const float* __restrict__ bq_a,
  const WT*    __restrict__ Wk_a, const float* __restrict__ bk_a,
  const WT*    __restrict__ Wv_a, const float* __restrict__ bv_a,
  const WT*    __restrict__ Wo_a, const float* __restrict__ bo_a,
  const float* __restrict__ g1_a, const float* __restrict__ be1_a,
  const WT*    __restrict__ W1_a, const float* __restrict__ b1_a,
  const WT*    __restrict__ W2_a, const float* __restrict__ b2_a,
  const float* __restrict__ g2_a, const float* __restrict__ be2_a,
  const float* __restrict__ PJw,  const float* __restrict__ PJb,
  float* __restrict__ dout)
{
  // Arena: predb | bufA | bufB(x_s at init) | k0 | v0 | k1 | v1 | k2 | v2 | tail
  // 30-row buffers; MFMA A-overreads of rows 30/31 land in the next region
  // (row-isolated, outputs masked). pred-f32 init staged over k0/v0 (pf).
  __shared__ __align__(16) u16 SH[9*BUFSZ + 2*SB];
  __shared__ float redA[4], redB[4], stats[2];

  u16* const predb = SH;
  u16* const bufA  = SH + BUFSZ;
  u16* const bufB  = SH + 2*BUFSZ;       // x_s during init; wo/f gemm outputs in layers

  const int tid  = threadIdx.x;
  const int wave = tid >> 6;         // 0..3
  const int lane = tid & 63;
  const int bi   = blockIdx.x;       // 0..5135 = b*321+c
  const int c    = bi % 321;
  const float* zr = z + bi*720;

  // ---- per-series mean/std over 720 samples ----
  float s=0.f, s2=0.f;
  for (int i=tid;i<720;i+=256){ float v=zr[i]; s+=v; s2+=v*v; }
  #pragma unroll
  for (int off=32; off>0; off>>=1){ s += __shfl_xor(s,off,64); s2 += __shfl_xor(s2,off,64); }
  if (lane==0){ redA[wave]=s; redB[wave]=s2; }
  __syncthreads();
  if (tid==0){
    float S=0.f,S2=0.f;
    #pragma unroll
    for (int w=0;w<4;++w){S+=redA[w];S2+=redB[w];}
    float mu = S*(1.f/720.f);
    float var = S2*(1.f/720.f) - mu*mu;
    stats[0]=mu; stats[1]=sqrtf(var+1e-5f);
  }
  __syncthreads();
  const float mu = stats[0], sd = stats[1], rsd = 1.f/sd;

  // ---- zn -> bufA (720 bf16, flat) ----
  for (int i=tid;i<720;i+=256) bufA[i] = f2bf((zr[i]-mu)*rsd);
  __syncthreads();

  // ---- patch embeds: x_s(->bufB) = zn-patches@WPw^T + WPb + PE ;
  //      pred = dummies[c]@WPw^T + WPb, f32 staged into pf (k0/v0 region) ----
  {
    float* pf = (float*)(SH + 3*BUFSZ);
    const int m = lane&15, qd = lane>>4;
    const short8 z8 = {0,0,0,0,0,0,0,0};
    #pragma unroll
    for (int ct=0;ct<2;++ct){
      const int col = ct*64 + wave*16 + m;
      short8 b = (qd<3) ? cvt8(WPw + col*24 + qd*8) : z8;   // K=24 pad 32
      const float bv = WPb[col];
      #pragma unroll
      for (int rt=0;rt<2;++rt){
        const int pm = rt*16+m;
        short8 ax = (pm<30 && qd<3) ? *(const short8*)(bufA + pm*24 + qd*8) : z8;
        short8 ap = (pm<30 && qd<3) ? cvt8(dums + c*720 + pm*24 + qd*8) : z8;
        floatx4 accx={0.f,0.f,0.f,0.f}, accp={0.f,0.f,0.f,0.f};
        accx = MFMA_BF16(ax,b,accx,0,0,0);
        accp = MFMA_BF16(ap,b,accp,0,0,0);
        #pragma unroll
        for (int r=0;r<4;++r){
          const int row = rt*16+qd*4+r;
          if (row<30){
            float pv = accp[r]+bv;
            bufB[row*SB+col]  = f2bf(accx[r]+bv+PE[row*128+col]);   // x_s
            pf[row*128+col]   = pv;
            predb[row*SB+col] = f2bf(pv);
          }
        }
      }
    }
  }
  __syncthreads();

  // ---- pred f32 -> registers (thread owns rows {wave+4k}, cols {lane,lane+64}) ----
  float p0[8], p1[8];
  {
    const float* pf = (const float*)(SH + 3*BUFSZ);
    #pragma unroll
    for (int idx=0; idx<8; ++idx){
      const int row = wave + idx*4;
      p0[idx] = (row<30) ? pf[row*128+lane]    : 0.f;
      p1[idx] = (row<30) ? pf[row*128+lane+64] : 0.f;
    }
  }
  __syncthreads();   // pf region freed -> k0/v0 usable

  // ---- cumulative attention scores (in log2 domain): thread owns (h,p),(h+8,p) ----
  float sc[2][30];
  #pragma unroll
  for (int s2i=0;s2i<2;++s2i)
    #pragma unroll
    for (int i=0;i<30;++i) sc[s2i][i]=0.f;
  const int h = wave*2 + (lane>>5);   // 0..7
  const int p = lane & 31;

  // ---- hoisted K/V for ALL 3 layers (x_s is layer-invariant): 3 gemms
  //      back-to-back, no barriers between -> load latencies overlap ----
  #pragma unroll
  for (int li=0; li<3; ++li){
    gemm_kv(bufB, Wk_a + li*16384, bk_a + li*128,
            Wv_a + li*16384, bv_a + li*128,
            SH + (3+2*li)*BUFSZ, SH + (4+2*li)*BUFSZ, wave, lane);
  }
  __syncthreads();

  for (int li=0; li<3; ++li){
    const WT* Wq = Wq_a + li*16384; const float* bq = bq_a + li*128;
    const WT* Wo = Wo_a + li*16384; const float* bo = bo_a + li*128;
    const WT* W1 = W1_a + li*32768; const float* b1 = b1_a + li*256;
    const WT* W2 = W2_a + li*16384; const float* b2 = b2_a + li*128;
    const u16* kb = SH + (3+2*li)*BUFSZ;
    const u16* vb = SH + (4+2*li)*BUFSZ;

    // q pre-scaled by ATTN_SCALE*log2e -> scores live in log2 domain;
    // softmax via exp2 is identical math (uniform logit scale cancels).
    gemm2(predb, Wq, bq, bufA, wave, lane, QSCALE);
    // NO barrier: attention reads only q cols written by its OWN wave
    // (he0 in wave's ct=0 col range, he1 in ct=1 range; K/V hoisted+synced).

    if (p < 30){
      const int he0 = h, he1 = h+8;
      // FUSED QK: both slots' dependent LDS chains in flight (+8 regs)
      short8 q0 = *(const short8*)(bufA + p*SB + he0*8);
      short8 q1 = *(const short8*)(bufA + p*SB + he1*8);
      const unsigned* qp0 = (const unsigned*)&q0;
      const unsigned* qp1 = (const unsigned*)&q1;
      #pragma unroll
      for (int si=0; si<30; ++si){
        short8 k0 = *(const short8*)(kb + si*SB + he0*8);
        short8 k1 = *(const short8*)(kb + si*SB + he1*8);
        const unsigned* kp0 = (const unsigned*)&k0;
        const unsigned* kp1 = (const unsigned*)&k1;
        sc[0][si] = dot2bf(qp0[0],kp0[0],
                    dot2bf(qp0[1],kp0[1],
                    dot2bf(qp0[2],kp0[2],
                    dot2bf(qp0[3],kp0[3], sc[0][si]))));
        sc[1][si] = dot2bf(qp1[0],kp1[0],
                    dot2bf(qp1[1],kp1[1],
                    dot2bf(qp1[2],kp1[2],
                    dot2bf(qp1[3],kp1[3], sc[1][si]))));
      }
      // per-slot softmax + V accumulation with depth-1 V prefetch
      // (register-light; r18 proved dual-slot V-fusion spills)
      #pragma unroll
      for (int s2i=0;s2i<2;++s2i){
        const int he = h + s2i*8;
        float mx = sc[s2i][0];
        #pragma unroll
        for (int si=1; si<30; ++si) mx = fmaxf(mx, sc[s2i][si]);
        float ssum = 0.f;
        float ov[8] = {0.f,0.f,0.f,0.f,0.f,0.f,0.f,0.f};
        short8 vv = *(const short8*)(vb + he*8);        // prefetch si=0
        #pragma unroll
        for (int si=0; si<30; ++si){
          short8 vcur = vv;
          if (si < 29) vv = *(const short8*)(vb + (si+1)*SB + he*8);  // prefetch next
          float e = exp2f(sc[s2i][si]-mx);
          ssum += e;
          #pragma unroll
          for (int j=0;j<8;++j) ov[j] += e*bf2f((u16)vcur[j]);
        }
        const float rn = 1.f/ssum;
        unsigned* ob32 = (unsigned*)(bufA + p*SB + he*8);
        #pragma unroll
        for (int jj=0;jj<4;++jj)
          ob32[jj] = pk2bf(ov[2*jj]*rn, ov[2*jj+1]*rn);  // o over own q slot
      }
    }
    __syncthreads();

    gemm2(bufA, Wo, bo, bufB, wave, lane, 1.f);               // wo = o@Wo^T+bo
    __syncthreads();
    ln_res_reg(p0, p1, bufB, predb, g1_a+li*128, be1_a+li*128, wave, lane);
    __syncthreads();

    gemm_h(predb, W1, b1, bufA, wave, lane);                  // ag = a*gelu(gate)
    __syncthreads();
    gemm2(bufA, W2, b2, bufB, wave, lane, 1.f);               // f = ag@W2^T+b2
    __syncthreads();
    ln_res_reg(p0, p1, bufB, predb, g2_a+li*128, be2_a+li*128, wave, lane);
    __syncthreads();
  }

  // ---- head: out = (pred@proj_w^T + proj_b)*sd + mu ; 4 tiles = 1 per wave ----
  {
    const int m = lane&15, qd = lane>>4;
    const short8 z8 = {0,0,0,0,0,0,0,0};
    const int rt = wave>>1, ct = wave&1;
    const int col = ct*16+m;                       // patch-len index 0..23 (pad 32)
    float* orow = dout + bi*720;
    floatx4 acc = {0.f,0.f,0.f,0.f};
    #pragma unroll
    for (int kt=0;kt<4;++kt){
      const int k0 = kt*32+qd*8;
      short8 a = *(const short8*)(predb + (rt*16+m)*SB + k0);
      short8 b = (col<24) ? cvt8(PJw + col*128 + k0) : z8;
      acc = MFMA_BF16(a,b,acc,0,0,0);
    }
    if (col<24){
      const float pb = PJb[col];
      #pragma unroll
      for (int r=0;r<4;++r){
        const int row = rt*16+qd*4+r;
        if (row<30) orow[row*24+col] = (acc[r]+pb)*sd + mu;
      }
    }
  }
}

extern "C" void kernel_launch(void* const* d_in, const int* in_sizes, int n_in,
                              void* d_out, int out_size, void* d_ws, size_t ws_size,
                              hipStream_t stream) {
  (void)in_sizes; (void)n_in; (void)out_size;
  const float* z    = (const float*)d_in[0];
  const float* WPw  = (const float*)d_in[1];
  const float* WPb  = (const float*)d_in[2];
  const float* PE   = (const float*)d_in[3];
  const float* dums = (const float*)d_in[4];
  const float* Wq   = (const float*)d_in[5];
  const float* bq   = (const float*)d_in[6];
  const float* Wk   = (const float*)d_in[7];
  const float* bk   = (const float*)d_in[8];
  const float* Wv   = (const float*)d_in[9];
  const float* bv   = (const float*)d_in[10];
  const float* Wo   = (const float*)d_in[11];
  const float* bo   = (const float*)d_in[12];
  const float* g1   = (const float*)d_in[13];
  const float* be1  = (const float*)d_in[14];
  const float* W1   = (const float*)d_in[15];
  const float* b1   = (const float*)d_in[16];
  const float* W2   = (const float*)d_in[17];
  const float* b2   = (const float*)d_in[18];
  const float* g2   = (const float*)d_in[19];
  const float* be2  = (const float*)d_in[20];
  const float* PJw  = (const float*)d_in[21];
  const float* PJb  = (const float*)d_in[22];
  float* dout = (float*)d_out;

  const size_t need = (size_t)344064 * sizeof(u16);   // 21*16384 bf16 weights
  if (ws_size >= need){
    u16* ws = (u16*)d_ws;
    cvtw<<<dim3(1344), dim3(256), 0, stream>>>(Wq, Wk, Wv, Wo, W1, W2, ws);
    ts_fused<u16><<<dim3(5136), dim3(256), 0, stream>>>(
      z, WPw, WPb, PE, dums,
      ws,        bq, ws+49152,  bk, ws+98304, bv, ws+147456, bo,
      g1, be1, ws+196608, b1, ws+294912, b2, g2, be2, PJw, PJb, dout);
  } else {
    ts_fused<float><<<dim3(5136), dim3(256), 0, stream>>>(
      z, WPw, WPb, PE, dums,
      Wq, bq, Wk, bk, Wv, bv, Wo, bo,
      g1, be1, W1, b1, W2, b2, g2, be2, PJw, PJb, dout);
  }
}

// Round 16
// 851.651 us; speedup vs baseline: 1.0212x; 1.0212x over previous
//
#include <hip/hip_runtime.h>
#include <math.h>

// PatchTST-style fused forward, f32 in/out, bf16 MFMA compute.
// Round-22: revert to r19 structure (852us overall / 816 steady — the
// frontier). r20/21 post-mortem: depth-1 V-prefetch + library exp2f cost
// +20us steady (816->838): the hand-pipelined V loop broke the compiler's
// schedule (consistent with r16's "intra-phase shaving is neutral/harmful"
// lesson) and exp2f() is the precise OCML call, not the raw instruction.
// Kept from r20, made strictly free: q pre-scaled by ATTN_SCALE*log2e and
// softmax exp via __builtin_amdgcn_exp2f (bare v_exp_f32 — removes the
// v_mul inside every __expf; zero extra registers, no conditionals).
// Ledger: 2 blk/CU frontier (HW {128,256} reg quantization); arch cap 128
// @ wpe(2); setprio -2% (r15); intra-phase shave neutral-to-harmful
// (r16/r21); K/V hoist +7us (r17); V-fusion spills (r14/r18); QK fusion +
// barrier cut -5us (r19); hand-prefetch -20us (r21).

typedef unsigned short u16;
typedef __attribute__((ext_vector_type(8))) short short8;
typedef __attribute__((ext_vector_type(4))) float floatx4;

// ATTN_SCALE * log2(e) = (8^-0.5) * 1.4426950408889634
#define QSCALE 0.5101087004564975f
#define SB 136        // bf16 LDS row stride: 272B = 68 dwords, 68%32=4 -> bank rotation
#define BUFSZ (30*SB) // one 30-row bf16 buffer, in u16 units

#define MFMA_BF16 __builtin_amdgcn_mfma_f32_16x16x32_bf16

__device__ __forceinline__ u16 f2bf(float f){
  union{ __bf16 b; u16 u; } v; v.b = (__bf16)f;   // RNE, hw cvt
  return v.u;
}
__device__ __forceinline__ float bf2f(u16 h){
  union{unsigned u; float f;} v; v.u = ((unsigned)h)<<16;
  return v.f;
}
// packed pair f32,f32 -> bf16x2 in one u32 (v_cvt_pk_bf16_f32)
__device__ __forceinline__ unsigned pk2bf(float lo, float hi){
  union{ __bf16 b[2]; unsigned u; } v;
  v.b[0] = (__bf16)lo; v.b[1] = (__bf16)hi;
  return v.u;
}
// d = a.bf16[0]*b.bf16[0] + a.bf16[1]*b.bf16[1] + c
__device__ __forceinline__ float dot2bf(unsigned a, unsigned b, float c){
  float d;
  asm("v_dot2_f32_bf16 %0, %1, %2, %3" : "=v"(d) : "v"(a), "v"(b), "v"(c));
  return d;
}
__device__ __forceinline__ float gelu_f(float x){   // tanh-form gelu (sigmoid identity)
  float u = x*(1.f + 0.044715f*x*x);
  float e = __expf(-1.5957691216057308f*u);
  return x/(1.f+e);
}

// 8 f32 -> bf16 fragment (16B-aligned source)
__device__ __forceinline__ short8 cvt8(const float* ap){
  floatx4 f0 = *(const floatx4*)ap;
  floatx4 f1 = *(const floatx4*)(ap+4);
  short8 a;
  a[0]=(short)f2bf(f0[0]); a[1]=(short)f2bf(f0[1]);
  a[2]=(short)f2bf(f0[2]); a[3]=(short)f2bf(f0[3]);
  a[4]=(short)f2bf(f1[0]); a[5]=(short)f2bf(f1[1]);
  a[6]=(short)f2bf(f1[2]); a[7]=(short)f2bf(f1[3]);
  return a;
}
__device__ __forceinline__ short8 loadB(const u16* p){ return *(const short8*)p; }
__device__ __forceinline__ short8 loadB(const float* p){ return cvt8(p); }

// store 4 acc rows ((acc+bias)*oscale) as bf16; rows >=30 skipped
__device__ __forceinline__ void epi(u16* out, floatx4 acc, float bv, float oscale,
                                    int rt, int qd, int col){
  #pragma unroll
  for (int r=0;r<4;++r){
    const int row = rt*16+qd*4+r;
    if (row<30) out[row*SB+col] = f2bf((acc[r]+bv)*oscale);
  }
}

// out(30x128) = A(30x128 LDS bf16, rows 30/31 read-over) @ W^T + bias, *oscale.
// 4 waves: wave covers cols {wave*16+m, 64+wave*16+m}; kt-outer, ct-batched.
template<typename WT>
__device__ __forceinline__ void gemm2(const u16* A, const WT* __restrict__ W,
                                      const float* __restrict__ bias, u16* out,
                                      int wave, int lane, float oscale){
  const int m=lane&15, qd=lane>>4, c0=wave*16+m;
  floatx4 acc[2][2] = {{{0.f,0.f,0.f,0.f},{0.f,0.f,0.f,0.f}},
                       {{0.f,0.f,0.f,0.f},{0.f,0.f,0.f,0.f}}};
  #pragma unroll
  for (int kt=0;kt<4;++kt){
    short8 b0 = loadB(W + c0*128       + kt*32 + qd*8);
    short8 b1 = loadB(W + (c0+64)*128  + kt*32 + qd*8);
    #pragma unroll
    for (int rt=0;rt<2;++rt){
      short8 a = *(const short8*)(A + (rt*16+m)*SB + kt*32 + qd*8);
      acc[0][rt] = MFMA_BF16(a, b0, acc[0][rt], 0,0,0);
      acc[1][rt] = MFMA_BF16(a, b1, acc[1][rt], 0,0,0);
    }
  }
  #pragma unroll
  for (int ct=0;ct<2;++ct){
    const int col = c0 + ct*64;
    const float bv = bias[col];
    #pragma unroll
    for (int rt=0;rt<2;++rt) epi(out, acc[ct][rt], bv, oscale, rt, qd, col);
  }
}

// k and v gemms from shared A = x_s
template<typename WT>
__device__ __forceinline__ void gemm_kv(const u16* A,
                                        const WT* __restrict__ Wk, const float* __restrict__ bk,
                                        const WT* __restrict__ Wv, const float* __restrict__ bv_,
                                        u16* outk, u16* outv, int wave, int lane){
  const int m=lane&15, qd=lane>>4, c0=wave*16+m;
  floatx4 acck[2][2] = {{{0.f,0.f,0.f,0.f},{0.f,0.f,0.f,0.f}},
                        {{0.f,0.f,0.f,0.f},{0.f,0.f,0.f,0.f}}};
  floatx4 accv[2][2] = {{{0.f,0.f,0.f,0.f},{0.f,0.f,0.f,0.f}},
                        {{0.f,0.f,0.f,0.f},{0.f,0.f,0.f,0.f}}};
  #pragma unroll
  for (int kt=0;kt<4;++kt){
    short8 bk0 = loadB(Wk + c0*128      + kt*32 + qd*8);
    short8 bk1 = loadB(Wk + (c0+64)*128 + kt*32 + qd*8);
    short8 bv0 = loadB(Wv + c0*128      + kt*32 + qd*8);
    short8 bv1 = loadB(Wv + (c0+64)*128 + kt*32 + qd*8);
    #pragma unroll
    for (int rt=0;rt<2;++rt){
      short8 a = *(const short8*)(A + (rt*16+m)*SB + kt*32 + qd*8);
      acck[0][rt] = MFMA_BF16(a, bk0, acck[0][rt], 0,0,0);
      acck[1][rt] = MFMA_BF16(a, bk1, acck[1][rt], 0,0,0);
      accv[0][rt] = MFMA_BF16(a, bv0, accv[0][rt], 0,0,0);
      accv[1][rt] = MFMA_BF16(a, bv1, accv[1][rt], 0,0,0);
    }
  }
  #pragma unroll
  for (int ct=0;ct<2;++ct){
    const int col = c0 + ct*64;
    const float bkb = bk[col], bvb = bv_[col];
    #pragma unroll
    for (int rt=0;rt<2;++rt){
      epi(outk, acck[ct][rt], bkb, 1.f, rt, qd, col);
      epi(outv, accv[ct][rt], bvb, 1.f, rt, qd, col);
    }
  }
}

// FF up: h = pred@W1^T (256 cols); writes ag = a * gelu(gate) directly.
template<typename WT>
__device__ __forceinline__ void gemm_h(const u16* A, const WT* __restrict__ W1,
                                       const float* __restrict__ b1, u16* out,
                                       int wave, int lane){
  const int m=lane&15, qd=lane>>4, c0=wave*16+m;
  floatx4 acca[2][2] = {{{0.f,0.f,0.f,0.f},{0.f,0.f,0.f,0.f}},
                        {{0.f,0.f,0.f,0.f},{0.f,0.f,0.f,0.f}}};
  floatx4 accg[2][2] = {{{0.f,0.f,0.f,0.f},{0.f,0.f,0.f,0.f}},
                        {{0.f,0.f,0.f,0.f},{0.f,0.f,0.f,0.f}}};
  #pragma unroll
  for (int kt=0;kt<4;++kt){
    short8 ba0 = loadB(W1 + c0*128        + kt*32 + qd*8);
    short8 ba1 = loadB(W1 + (c0+64)*128   + kt*32 + qd*8);
    short8 bg0 = loadB(W1 + (c0+128)*128  + kt*32 + qd*8);
    short8 bg1 = loadB(W1 + (c0+192)*128  + kt*32 + qd*8);
    #pragma unroll
    for (int rt=0;rt<2;++rt){
      short8 a = *(const short8*)(A + (rt*16+m)*SB + kt*32 + qd*8);
      acca[0][rt] = MFMA_BF16(a, ba0, acca[0][rt], 0,0,0);
      acca[1][rt] = MFMA_BF16(a, ba1, acca[1][rt], 0,0,0);
      accg[0][rt] = MFMA_BF16(a, bg0, accg[0][rt], 0,0,0);
      accg[1][rt] = MFMA_BF16(a, bg1, accg[1][rt], 0,0,0);
    }
  }
  #pragma unroll
  for (int ct=0;ct<2;++ct){
    const int ca = c0 + ct*64;
    const float bab = b1[ca], bgb = b1[128+ca];
    #pragma unroll
    for (int rt=0;rt<2;++rt){
      #pragma unroll
      for (int r=0;r<4;++r){
        const int row = rt*16+qd*4+r;
        if (row<30){
          float a = acca[ct][rt][r]+bab;
          float g = accg[ct][rt][r]+bgb;
          out[row*SB+ca] = f2bf(a * gelu_f(g));
        }
      }
    }
  }
}

// pred = LN(pred + bf16(add)) * g + be; pred lives in registers p0/p1
// (thread owns rows {wave+4k}, cols {lane, lane+64}); maintains predb mirror.
__device__ __forceinline__ void ln_res_reg(float (&p0)[8], float (&p1)[8],
                                           const u16* add, u16* predb,
                                           const float* __restrict__ g, const float* __restrict__ be,
                                           int wave, int lane){
  #pragma unroll
  for (int idx=0; idx<8; ++idx){
    const int row = wave + idx*4;
    if (row < 30){
      float v0 = p0[idx] + bf2f(add[row*SB+lane]);
      float v1 = p1[idx] + bf2f(add[row*SB+lane+64]);
      float s = v0+v1, s2 = v0*v0+v1*v1;
      #pragma unroll
      for (int off=32; off>0; off>>=1){ s += __shfl_xor(s,off,64); s2 += __shfl_xor(s2,off,64); }
      float m = s*(1.f/128.f);
      float var = s2*(1.f/128.f) - m*m;
      float rstd = rsqrtf(var + 1e-5f);
      float o0 = (v0-m)*rstd*g[lane]    + be[lane];
      float o1 = (v1-m)*rstd*g[lane+64] + be[lane+64];
      p0[idx] = o0; p1[idx] = o1;
      predb[row*SB+lane]    = f2bf(o0);
      predb[row*SB+lane+64] = f2bf(o1);
    }
  }
}

// f32 -> bf16 weight staging
__global__ void cvtw(const float* __restrict__ Wq, const float* __restrict__ Wk,
                     const float* __restrict__ Wv, const float* __restrict__ Wo,
                     const float* __restrict__ W1, const float* __restrict__ W2,
                     u16* __restrict__ ws){
  const int i = blockIdx.x*256 + threadIdx.x;   // grid covers exactly 344064
  float v;
  if      (i < 49152)  v = Wq[i];
  else if (i < 98304)  v = Wk[i-49152];
  else if (i < 147456) v = Wv[i-98304];
  else if (i < 196608) v = Wo[i-147456];
  else if (i < 294912) v = W1[i-196608];
  else                 v = W2[i-294912];
  ws[i] = f2bf(v);
}

template<typename WT>
__global__ void
__attribute__((amdgpu_flat_work_group_size(256,256), amdgpu_waves_per_eu(2)))
ts_fused(
  const float* __restrict__ z,    const float* __restrict__ WPw, const float* __restrict__ WPb,
  const float* __restrict__ PE,   const float* __restrict__ dums,
  const WT*    __restrict__ Wq_a, const float* __restrict__ bq_a,
  const WT*    __restrict__ Wk_a, const float* __restrict__ bk_a,
  const WT*    __restrict__ Wv_a, const float* __restrict__ bv_a,
  const WT*    __restrict__ Wo_a, const float* __restrict__ bo_a,
  const float* __restrict__ g1_a, const float* __restrict__ be1_a,
  const WT*    __restrict__ W1_a, const float* __restrict__ b1_a,
  const WT*    __restrict__ W2_a, const float* __restrict__ b2_a,
  const float* __restrict__ g2_a, const float* __restrict__ be2_a,
  const float* __restrict__ PJw,  const float* __restrict__ PJb,
  float* __restrict__ dout)
{
  // Arena: predb | bufA | bufB(x_s at init) | k0 | v0 | k1 | v1 | k2 | v2 | tail
  // 30-row buffers; MFMA A-overreads of rows 30/31 land in the next region
  // (row-isolated, outputs masked). pred-f32 init staged over k0/v0 (pf).
  __shared__ __align__(16) u16 SH[9*BUFSZ + 2*SB];
  __shared__ float redA[4], redB[4], stats[2];

  u16* const predb = SH;
  u16* const bufA  = SH + BUFSZ;
  u16* const bufB  = SH + 2*BUFSZ;       // x_s during init; wo/f gemm outputs in layers

  const int tid  = threadIdx.x;
  const int wave = tid >> 6;         // 0..3
  const int lane = tid & 63;
  const int bi   = blockIdx.x;       // 0..5135 = b*321+c
  const int c    = bi % 321;
  const float* zr = z + bi*720;

  // ---- per-series mean/std over 720 samples ----
  float s=0.f, s2=0.f;
  for (int i=tid;i<720;i+=256){ float v=zr[i]; s+=v; s2+=v*v; }
  #pragma unroll
  for (int off=32; off>0; off>>=1){ s += __shfl_xor(s,off,64); s2 += __shfl_xor(s2,off,64); }
  if (lane==0){ redA[wave]=s; redB[wave]=s2; }
  __syncthreads();
  if (tid==0){
    float S=0.f,S2=0.f;
    #pragma unroll
    for (int w=0;w<4;++w){S+=redA[w];S2+=redB[w];}
    float mu = S*(1.f/720.f);
    float var = S2*(1.f/720.f) - mu*mu;
    stats[0]=mu; stats[1]=sqrtf(var+1e-5f);
  }
  __syncthreads();
  const float mu = stats[0], sd = stats[1], rsd = 1.f/sd;

  // ---- zn -> bufA (720 bf16, flat) ----
  for (int i=tid;i<720;i+=256) bufA[i] = f2bf((zr[i]-mu)*rsd);
  __syncthreads();

  // ---- patch embeds: x_s(->bufB) = zn-patches@WPw^T + WPb + PE ;
  //      pred = dummies[c]@WPw^T + WPb, f32 staged into pf (k0/v0 region) ----
  {
    float* pf = (float*)(SH + 3*BUFSZ);
    const int m = lane&15, qd = lane>>4;
    const short8 z8 = {0,0,0,0,0,0,0,0};
    #pragma unroll
    for (int ct=0;ct<2;++ct){
      const int col = ct*64 + wave*16 + m;
      short8 b = (qd<3) ? cvt8(WPw + col*24 + qd*8) : z8;   // K=24 pad 32
      const float bv = WPb[col];
      #pragma unroll
      for (int rt=0;rt<2;++rt){
        const int pm = rt*16+m;
        short8 ax = (pm<30 && qd<3) ? *(const short8*)(bufA + pm*24 + qd*8) : z8;
        short8 ap = (pm<30 && qd<3) ? cvt8(dums + c*720 + pm*24 + qd*8) : z8;
        floatx4 accx={0.f,0.f,0.f,0.f}, accp={0.f,0.f,0.f,0.f};
        accx = MFMA_BF16(ax,b,accx,0,0,0);
        accp = MFMA_BF16(ap,b,accp,0,0,0);
        #pragma unroll
        for (int r=0;r<4;++r){
          const int row = rt*16+qd*4+r;
          if (row<30){
            float pv = accp[r]+bv;
            bufB[row*SB+col]  = f2bf(accx[r]+bv+PE[row*128+col]);   // x_s
            pf[row*128+col]   = pv;
            predb[row*SB+col] = f2bf(pv);
          }
        }
      }
    }
  }
  __syncthreads();

  // ---- pred f32 -> registers (thread owns rows {wave+4k}, cols {lane,lane+64}) ----
  float p0[8], p1[8];
  {
    const float* pf = (const float*)(SH + 3*BUFSZ);
    #pragma unroll
    for (int idx=0; idx<8; ++idx){
      const int row = wave + idx*4;
      p0[idx] = (row<30) ? pf[row*128+lane]    : 0.f;
      p1[idx] = (row<30) ? pf[row*128+lane+64] : 0.f;
    }
  }
  __syncthreads();   // pf region freed -> k0/v0 usable

  // ---- cumulative attention scores (in log2 domain): thread owns (h,p),(h+8,p) ----
  float sc[2][30];
  #pragma unroll
  for (int s2i=0;s2i<2;++s2i)
    #pragma unroll
    for (int i=0;i<30;++i) sc[s2i][i]=0.f;
  const int h = wave*2 + (lane>>5);   // 0..7
  const int p = lane & 31;

  // ---- hoisted K/V for ALL 3 layers (x_s is layer-invariant): 3 gemms
  //      back-to-back, no barriers between -> load latencies overlap ----
  #pragma unroll
  for (int li=0; li<3; ++li){
    gemm_kv(bufB, Wk_a + li*16384, bk_a + li*128,
            Wv_a + li*16384, bv_a + li*128,
            SH + (3+2*li)*BUFSZ, SH + (4+2*li)*BUFSZ, wave, lane);
  }
  __syncthreads();

  for (int li=0; li<3; ++li){
    const WT* Wq = Wq_a + li*16384; const float* bq = bq_a + li*128;
    const WT* Wo = Wo_a + li*16384; const float* bo = bo_a + li*128;
    const WT* W1 = W1_a + li*32768; const float* b1 = b1_a + li*256;
    const WT* W2 = W2_a + li*16384; const float* b2 = b2_a + li*128;
    const u16* kb = SH + (3+2*li)*BUFSZ;
    const u16* vb = SH + (4+2*li)*BUFSZ;

    // q pre-scaled by ATTN_SCALE*log2e -> scores live in log2 domain;
    // softmax via raw v_exp_f32 (exp2) is identical math (uniform logit
    // scale cancels in the ratio; consistent across accumulated layers).
    gemm2(predb, Wq, bq, bufA, wave, lane, QSCALE);
    // NO barrier: attention reads only q cols written by its OWN wave
    // (he0 in wave's ct=0 col range, he1 in ct=1 range; K/V hoisted+synced).

    if (p < 30){
      const int he0 = h, he1 = h+8;
      // FUSED QK: both slots' dependent LDS chains in flight (+8 regs)
      short8 q0 = *(const short8*)(bufA + p*SB + he0*8);
      short8 q1 = *(const short8*)(bufA + p*SB + he1*8);
      const unsigned* qp0 = (const unsigned*)&q0;
      const unsigned* qp1 = (const unsigned*)&q1;
      #pragma unroll
      for (int si=0; si<30; ++si){
        short8 k0 = *(const short8*)(kb + si*SB + he0*8);
        short8 k1 = *(const short8*)(kb + si*SB + he1*8);
        const unsigned* kp0 = (const unsigned*)&k0;
        const unsigned* kp1 = (const unsigned*)&k1;
        sc[0][si] = dot2bf(qp0[0],kp0[0],
                    dot2bf(qp0[1],kp0[1],
                    dot2bf(qp0[2],kp0[2],
                    dot2bf(qp0[3],kp0[3], sc[0][si]))));
        sc[1][si] = dot2bf(qp1[0],kp1[0],
                    dot2bf(qp1[1],kp1[1],
                    dot2bf(qp1[2],kp1[2],
                    dot2bf(qp1[3],kp1[3], sc[1][si]))));
      }
      // per-slot softmax + V accumulation (plain loop — the compiler
      // schedules this better than hand-prefetch did, r21 lesson)
      #pragma unroll
      for (int s2i=0;s2i<2;++s2i){
        const int he = h + s2i*8;
        float mx = sc[s2i][0];
        #pragma unroll
        for (int si=1; si<30; ++si) mx = fmaxf(mx, sc[s2i][si]);
        float ssum = 0.f;
        float ov[8] = {0.f,0.f,0.f,0.f,0.f,0.f,0.f,0.f};
        #pragma unroll
        for (int si=0; si<30; ++si){
          float e = __builtin_amdgcn_exp2f(sc[s2i][si]-mx);   // raw v_exp_f32
          ssum += e;
          short8 vv = *(const short8*)(vb + si*SB + he*8);
          #pragma unroll
          for (int j=0;j<8;++j) ov[j] += e*bf2f((u16)vv[j]);
        }
        const float rn = 1.f/ssum;
        unsigned* ob32 = (unsigned*)(bufA + p*SB + he*8);
        #pragma unroll
        for (int jj=0;jj<4;++jj)
          ob32[jj] = pk2bf(ov[2*jj]*rn, ov[2*jj+1]*rn);  // o over own q slot
      }
    }
    __syncthreads();

    gemm2(bufA, Wo, bo, bufB, wave, lane, 1.f);               // wo = o@Wo^T+bo
    __syncthreads();
    ln_res_reg(p0, p1, bufB, predb, g1_a+li*128, be1_a+li*128, wave, lane);
    __syncthreads();

    gemm_h(predb, W1, b1, bufA, wave, lane);                  // ag = a*gelu(gate)
    __syncthreads();
    gemm2(bufA, W2, b2, bufB, wave, lane, 1.f);               // f = ag@W2^T+b2
    __syncthreads();
    ln_res_reg(p0, p1, bufB, predb, g2_a+li*128, be2_a+li*128, wave, lane);
    __syncthreads();
  }

  // ---- head: out = (pred@proj_w^T + proj_b)*sd + mu ; 4 tiles = 1 per wave ----
  {
    const int m = lane&15, qd = lane>>4;
    const short8 z8 = {0,0,0,0,0,0,0,0};
    const int rt = wave>>1, ct = wave&1;
    const int col = ct*16+m;                       // patch-len index 0..23 (pad 32)
    float* orow = dout + bi*720;
    floatx4 acc = {0.f,0.f,0.f,0.f};
    #pragma unroll
    for (int kt=0;kt<4;++kt){
      const int k0 = kt*32+qd*8;
      short8 a = *(const short8*)(predb + (rt*16+m)*SB + k0);
      short8 b = (col<24) ? cvt8(PJw + col*128 + k0) : z8;
      acc = MFMA_BF16(a,b,acc,0,0,0);
    }
    if (col<24){
      const float pb = PJb[col];
      #pragma unroll
      for (int r=0;r<4;++r){
        const int row = rt*16+qd*4+r;
        if (row<30) orow[row*24+col] = (acc[r]+pb)*sd + mu;
      }
    }
  }
}

extern "C" void kernel_launch(void* const* d_in, const int* in_sizes, int n_in,
                              void* d_out, int out_size, void* d_ws, size_t ws_size,
                              hipStream_t stream) {
  (void)in_sizes; (void)n_in; (void)out_size;
  const float* z    = (const float*)d_in[0];
  const float* WPw  = (const float*)d_in[1];
  const float* WPb  = (const float*)d_in[2];
  const float* PE   = (const float*)d_in[3];
  const float* dums = (const float*)d_in[4];
  const float* Wq   = (const float*)d_in[5];
  const float* bq   = (const float*)d_in[6];
  const float* Wk   = (const float*)d_in[7];
  const float* bk   = (const float*)d_in[8];
  const float* Wv   = (const float*)d_in[9];
  const float* bv   = (const float*)d_in[10];
  const float* Wo   = (const float*)d_in[11];
  const float* bo   = (const float*)d_in[12];
  const float* g1   = (const float*)d_in[13];
  const float* be1  = (const float*)d_in[14];
  const float* W1   = (const float*)d_in[15];
  const float* b1   = (const float*)d_in[16];
  const float* W2   = (const float*)d_in[17];
  const float* b2   = (const float*)d_in[18];
  const float* g2   = (const float*)d_in[19];
  const float* be2  = (const float*)d_in[20];
  const float* PJw  = (const float*)d_in[21];
  const float* PJb  = (const float*)d_in[22];
  float* dout = (float*)d_out;

  const size_t need = (size_t)344064 * sizeof(u16);   // 21*16384 bf16 weights
  if (ws_size >= need){
    u16* ws = (u16*)d_ws;
    cvtw<<<dim3(1344), dim3(256), 0, stream>>>(Wq, Wk, Wv, Wo, W1, W2, ws);
    ts_fused<u16><<<dim3(5136), dim3(256), 0, stream>>>(
      z, WPw, WPb, PE, dums,
      ws,        bq, ws+49152,  bk, ws+98304, bv, ws+147456, bo,
      g1, be1, ws+196608, b1, ws+294912, b2, g2, be2, PJw, PJb, dout);
  } else {
    ts_fused<float><<<dim3(5136), dim3(256), 0, stream>>>(
      z, WPw, WPb, PE, dums,
      Wq, bq, Wk, bk, Wv, bv, Wo, bo,
      g1, be1, W1, b1, W2, b2, g2, be2, PJw, PJb, dout);
  }
}